// Round 1
// baseline (280.569 us; speedup 1.0000x reference)
//
#include <hip/hip_runtime.h>
#include <cstdint>
#include <cstddef>

typedef unsigned short u16;
typedef unsigned int   u32;
typedef __attribute__((ext_vector_type(8))) short bf16x8;
typedef __attribute__((ext_vector_type(4))) float f32x4;

#define D_IN  256
#define D_H   128
#define D_OUT 64

__device__ __forceinline__ float bf2f(u16 u){
  union { u32 i; float f; } v; v.i = ((u32)u) << 16; return v.f;
}
__device__ __forceinline__ u16 f2bf(float f){
  union { float f; u32 i; } v; v.f = f;
  u32 r = (v.i + 0x7fffu + ((v.i >> 16) & 1u)) >> 16;
  return (u16)r;
}

// ---------------- weight prep + deg zero (fused) ----------------
__global__ void k_wprep(const float* __restrict__ W0, const float* __restrict__ W1,
                        u16* __restrict__ W0t, u16* __restrict__ W1t,
                        int* __restrict__ deg, int n_t){
  int i = blockIdx.x * 256 + threadIdx.x;
  if (i < 128 * 256){
    int n = i >> 8, k = i & 255;
    W0t[i] = f2bf(W0[(size_t)k * 128 + n]);
  } else if (i < 128 * 256 + 64 * 128){
    int j = i - 128 * 256;
    int n = j >> 7, k = j & 127;
    W1t[j] = f2bf(W1[(size_t)k * 64 + n]);
  } else if (i - (128 * 256 + 64 * 128) < n_t){
    deg[i - (128 * 256 + 64 * 128)] = 0;
  }
}

// ---------------- graph prep ----------------
__global__ void k_deg(const int* __restrict__ dst, int E, int* __restrict__ deg){
  int e = blockIdx.x * 256 + threadIdx.x;
  if (e < E) atomicAdd(&deg[dst[e]], 1);
}

__global__ __launch_bounds__(256) void k_bsum(const int* __restrict__ deg, int N,
                                              int* __restrict__ bsum){
  __shared__ int s[256];
  int tid = threadIdx.x;
  int i = blockIdx.x * 256 + tid;
  s[tid] = (i < N) ? deg[i] : 0;
  __syncthreads();
  for (int o = 128; o > 0; o >>= 1){
    if (tid < o) s[tid] += s[tid + o];
    __syncthreads();
  }
  if (tid == 0) bsum[blockIdx.x] = s[0];
}

__global__ __launch_bounds__(256) void k_off(const int* __restrict__ deg, int N,
                                             const int* __restrict__ bsum, int nb,
                                             int* __restrict__ off, int* __restrict__ cursor,
                                             float* __restrict__ dinv){
  __shared__ int s[256];
  __shared__ int sbase[256];
  const int tid = threadIdx.x;
  const int bid = blockIdx.x;
  const int i   = bid * 256 + tid;
  int acc = 0;
  for (int j = tid; j < bid; j += 256) acc += bsum[j];
  sbase[tid] = acc;
  int v = (i < N) ? deg[i] : 0;
  s[tid] = v;
  __syncthreads();
  for (int o = 128; o > 0; o >>= 1){
    if (tid < o) sbase[tid] += sbase[tid + o];
    __syncthreads();
  }
  for (int o = 1; o < 256; o <<= 1){
    int t = (tid >= o) ? s[tid - o] : 0;
    __syncthreads();
    s[tid] += t;
    __syncthreads();
  }
  if (i < N){
    int excl = s[tid] - v + sbase[0];
    off[i] = excl;
    cursor[i] = excl;
    dinv[i] = rsqrtf((float)v + 1.0f);
  }
}

__global__ void k_fill(const int* __restrict__ src, const int* __restrict__ dst,
                       int E, int* __restrict__ cursor, int* __restrict__ csr){
  int e = blockIdx.x * 256 + threadIdx.x;
  if (e < E){
    int d = dst[e];
    int p = atomicAdd(&cursor[d], 1);
    csr[p] = src[e];
  }
}

// ---------------- GEMM1: barrier-free, LDS-free. wave tile 32x128 ----------------
// A (f32) frags loaded global->reg with in-reg bf16 convert; B (bf16, 64 KB,
// L2-resident) frags loaded global->reg. Register double-buffer, 1 K-step ahead.
__global__ __launch_bounds__(256) void k_gemm1(
    const float* __restrict__ Xs, const float* __restrict__ Xt,
    const u16* __restrict__ W0t, int M, int n_s,
    u16* __restrict__ out)
{
  const int t    = threadIdx.x;
  const int wave = t >> 6, lane = t & 63;
  const int lm   = lane & 15, quad = lane >> 4;
  const int rowW = blockIdx.x * 128 + wave * 32;

  // per-lane A row pointers for the two m-fragments (clamped; stores are guarded)
  const float* pa0;
  const float* pa1;
  {
    int r0 = rowW + lm;       int c0 = (r0 < M) ? r0 : 0;
    int r1 = rowW + 16 + lm;  int c1 = (r1 < M) ? r1 : 0;
    pa0 = ((c0 < n_s) ? (Xs + (size_t)c0 * D_IN) : (Xt + (size_t)(c0 - n_s) * D_IN)) + quad * 8;
    pa1 = ((c1 < n_s) ? (Xs + (size_t)c1 * D_IN) : (Xt + (size_t)(c1 - n_s) * D_IN)) + quad * 8;
  }
  const u16* pb = W0t + (size_t)lm * D_IN + quad * 8;

  f32x4 acc[2][8];
  const f32x4 z = {0.f, 0.f, 0.f, 0.f};
  #pragma unroll
  for (int i = 0; i < 2; i++)
    #pragma unroll
    for (int j = 0; j < 8; j++) acc[i][j] = z;

  float4 a[2][4];
  int4   b[2][8];

  // prologue: K-step 0
  a[0][0] = *(const float4*)(pa0);
  a[0][1] = *(const float4*)(pa0 + 4);
  a[0][2] = *(const float4*)(pa1);
  a[0][3] = *(const float4*)(pa1 + 4);
  #pragma unroll
  for (int nf = 0; nf < 8; nf++)
    b[0][nf] = *(const int4*)(pb + (size_t)nf * 16 * D_IN);

  #pragma unroll
  for (int kk = 0; kk < 8; kk++){
    const int cur = kk & 1, nxt = cur ^ 1;
    if (kk < 7){
      const int ko = (kk + 1) * 32;
      a[nxt][0] = *(const float4*)(pa0 + ko);
      a[nxt][1] = *(const float4*)(pa0 + ko + 4);
      a[nxt][2] = *(const float4*)(pa1 + ko);
      a[nxt][3] = *(const float4*)(pa1 + ko + 4);
      #pragma unroll
      for (int nf = 0; nf < 8; nf++)
        b[nxt][nf] = *(const int4*)(pb + (size_t)nf * 16 * D_IN + ko);
    }
    bf16x8 af[2];
    #pragma unroll
    for (int mi = 0; mi < 2; mi++){
      const float* fa = (const float*)&a[cur][mi * 2];
      u16 tmp[8];
      #pragma unroll
      for (int q = 0; q < 8; q++) tmp[q] = f2bf(fa[q]);
      af[mi] = *(const bf16x8*)tmp;
    }
    #pragma unroll
    for (int mi = 0; mi < 2; mi++)
      #pragma unroll
      for (int nf = 0; nf < 8; nf++)
        acc[mi][nf] = __builtin_amdgcn_mfma_f32_16x16x32_bf16(
            af[mi], *(const bf16x8*)&b[cur][nf], acc[mi][nf], 0, 0, 0);
  }

  #pragma unroll
  for (int mi = 0; mi < 2; mi++){
    int rbase = rowW + mi * 16 + quad * 4;
    #pragma unroll
    for (int rr = 0; rr < 4; rr++){
      int m = rbase + rr;
      if (m >= M) continue;
      u16* op = out + (size_t)m * D_H + lm;
      #pragma unroll
      for (int nf = 0; nf < 8; nf++)
        op[nf * 16] = f2bf(acc[mi][nf][rr]);
    }
  }
}

// ---------------- fused aggregation (wide gather): one wave per dst node ----------------
__global__ __launch_bounds__(256) void k_aggf(
    const int* __restrict__ off, const int* __restrict__ deg,
    const int* __restrict__ csr, const float* __restrict__ dinv,
    u16* __restrict__ h1, int n_s, int n_t)
{
  int w    = (blockIdx.x * 256 + threadIdx.x) >> 6;
  int lane = threadIdx.x & 63;
  if (w >= n_t) return;
  const int g = lane >> 4;
  const int c = lane & 15;
  int start = off[w];
  int n     = deg[w];

  float r[8], p[8];
  #pragma unroll
  for (int q = 0; q < 8; q++){ r[q] = 0.f; p[q] = 0.f; }

  int i = 0;
  for (; i + 8 <= n; i += 8){
    int sa = csr[start + i + g];
    int sb = csr[start + i + 4 + g];
    int4 da = *(const int4*)(h1 + (size_t)sa * D_H + c * 8);
    int4 db = *(const int4*)(h1 + (size_t)sb * D_H + c * 8);
    const u16* ha = (const u16*)&da;
    const u16* hb = (const u16*)&db;
    #pragma unroll
    for (int q = 0; q < 8; q++){
      float va = bf2f(ha[q]), vb = bf2f(hb[q]);
      r[q] += va + vb;
      p[q] += fmaxf(va, 0.f) + fmaxf(vb, 0.f);
    }
  }
  for (; i < n; i += 4){
    if (i + g < n){
      int sa = csr[start + i + g];
      int4 da = *(const int4*)(h1 + (size_t)sa * D_H + c * 8);
      const u16* ha = (const u16*)&da;
      #pragma unroll
      for (int q = 0; q < 8; q++){
        float va = bf2f(ha[q]);
        r[q] += va;
        p[q] += fmaxf(va, 0.f);
      }
    }
  }

  #pragma unroll
  for (int q = 0; q < 8; q++){
    r[q] += __shfl_xor(r[q], 16, 64);
    r[q] += __shfl_xor(r[q], 32, 64);
    p[q] += __shfl_xor(p[q], 16, 64);
    p[q] += __shfl_xor(p[q], 32, 64);
  }

  if (g == 0){
    float di  = dinv[w];
    float di2 = di * di;
    u16* selfp = h1 + (size_t)(n_s + w) * D_H + c * 8;
    int4 hs = *(const int4*)selfp;
    const u16* hh = (const u16*)&hs;
    u16 ob[8];
    #pragma unroll
    for (int q = 0; q < 8; q++){
      float zq = fmaxf(di * r[q] + di2 * bf2f(hh[q]), 0.f);
      float uq = di * p[q] + di2 * zq;
      ob[q] = f2bf(uq);
    }
    *(int4*)selfp = *(int4*)ob;
  }
}

// ---------------- GEMM2: barrier-free, LDS-free. wave tile 32x64 ----------------
// A (bf16 h1) frags loaded global->reg with per-lane ReLU (rows < n_s);
// B (W1t, 16 KB, L1-resident) frags loaded global->reg. Double-buffered.
__device__ __forceinline__ bf16x8 relu_bf(int4 v, bool relu){
  const u16* s = (const u16*)&v;
  u16 tmp[8];
  #pragma unroll
  for (int q = 0; q < 8; q++){
    u16 x = s[q];
    tmp[q] = (relu && (x & 0x8000u)) ? (u16)0 : x;
  }
  return *(const bf16x8*)tmp;
}

__global__ __launch_bounds__(256) void k_gemm2(
    const u16* __restrict__ h1, const u16* __restrict__ W1t,
    int M, int n_s, float* __restrict__ out)
{
  const int t    = threadIdx.x;
  const int wave = t >> 6, lane = t & 63;
  const int lm   = lane & 15, quad = lane >> 4;
  const int rowW = blockIdx.x * 128 + wave * 32;

  int r0 = rowW + lm, r1 = rowW + 16 + lm;
  const bool relu0 = (r0 < n_s), relu1 = (r1 < n_s);
  int c0 = (r0 < M) ? r0 : 0, c1 = (r1 < M) ? r1 : 0;
  const u16* pa0 = h1 + (size_t)c0 * D_H + quad * 8;
  const u16* pa1 = h1 + (size_t)c1 * D_H + quad * 8;
  const u16* pb  = W1t + (size_t)lm * D_H + quad * 8;

  f32x4 acc[2][4];
  const f32x4 z = {0.f, 0.f, 0.f, 0.f};
  #pragma unroll
  for (int i = 0; i < 2; i++)
    #pragma unroll
    for (int j = 0; j < 4; j++) acc[i][j] = z;

  int4 a[2][2], b[2][4];
  a[0][0] = *(const int4*)(pa0);
  a[0][1] = *(const int4*)(pa1);
  #pragma unroll
  for (int nf = 0; nf < 4; nf++)
    b[0][nf] = *(const int4*)(pb + (size_t)nf * 16 * D_H);

  #pragma unroll
  for (int kk = 0; kk < 4; kk++){
    const int cur = kk & 1, nxt = cur ^ 1;
    if (kk < 3){
      const int ko = (kk + 1) * 32;
      a[nxt][0] = *(const int4*)(pa0 + ko);
      a[nxt][1] = *(const int4*)(pa1 + ko);
      #pragma unroll
      for (int nf = 0; nf < 4; nf++)
        b[nxt][nf] = *(const int4*)(pb + (size_t)nf * 16 * D_H + ko);
    }
    bf16x8 af[2];
    af[0] = relu_bf(a[cur][0], relu0);
    af[1] = relu_bf(a[cur][1], relu1);
    #pragma unroll
    for (int mi = 0; mi < 2; mi++)
      #pragma unroll
      for (int nf = 0; nf < 4; nf++)
        acc[mi][nf] = __builtin_amdgcn_mfma_f32_16x16x32_bf16(
            af[mi], *(const bf16x8*)&b[cur][nf], acc[mi][nf], 0, 0, 0);
  }

  #pragma unroll
  for (int mi = 0; mi < 2; mi++){
    int rbase = rowW + mi * 16 + quad * 4;
    #pragma unroll
    for (int rr = 0; rr < 4; rr++){
      int m = rbase + rr;
      if (m >= M) continue;
      float* op = out + (size_t)m * D_OUT + lm;
      #pragma unroll
      for (int nf = 0; nf < 4; nf++)
        op[nf * 16] = acc[mi][nf][rr];
    }
  }
}

static inline size_t alup(size_t x){ return (x + 255) & ~(size_t)255; }

extern "C" void kernel_launch(void* const* d_in, const int* in_sizes, int n_in,
                              void* d_out, int out_size, void* d_ws, size_t ws_size,
                              hipStream_t stream)
{
  const int*   ei = (const int*)d_in[0];
  const float* xs = (const float*)d_in[1];
  const float* xt = (const float*)d_in[2];
  const float* W0 = (const float*)d_in[3];
  const float* W1 = (const float*)d_in[4];
  const int E   = in_sizes[0] / 2;
  const int n_s = in_sizes[1] / D_IN;
  const int n_t = in_sizes[2] / D_IN;
  const int M   = n_s + n_t;
  const int* src = ei;       // edge_index row 0
  const int* dst = ei + E;   // edge_index row 1 (0-based target index)
  const int nb_t = (n_t + 255) / 256;

  // workspace layout (~29 MB)
  char* p = (char*)d_ws;
  int*   deg    = (int*)p;    p += alup((size_t)n_t * 4);
  int*   off    = (int*)p;    p += alup((size_t)n_t * 4);
  int*   cursor = (int*)p;    p += alup((size_t)n_t * 4);
  float* dinv   = (float*)p;  p += alup((size_t)n_t * 4);
  int*   bsum   = (int*)p;    p += alup((size_t)nb_t * 4);
  int*   csr    = (int*)p;    p += alup((size_t)E * 4);
  u16*   W0t    = (u16*)p;    p += alup((size_t)D_H * D_IN * 2);
  u16*   W1t    = (u16*)p;    p += alup((size_t)D_OUT * D_H * 2);
  u16*   h1     = (u16*)p;    p += alup((size_t)M * D_H * 2);

  const int wprep_n = 128*256 + 64*128 + n_t;
  k_wprep <<<(wprep_n + 255) / 256, 256, 0, stream>>>(W0, W1, W0t, W1t, deg, n_t);
  k_deg   <<<(E + 255) / 256, 256, 0, stream>>>(dst, E, deg);
  k_bsum  <<<nb_t, 256, 0, stream>>>(deg, n_t, bsum);
  k_off   <<<nb_t, 256, 0, stream>>>(deg, n_t, bsum, nb_t, off, cursor, dinv);
  k_fill  <<<(E + 255) / 256, 256, 0, stream>>>(src, dst, E, cursor, csr);

  // layer 1: h1 = X @ W0 (raw, all rows, bf16)
  k_gemm1<<<(M + 127) / 128, 256, 0, stream>>>(xs, xt, W0t, M, n_s, h1);
  // fused agg: h1 target rows <- u_t (single gather pass for both layers)
  k_aggf <<<(n_t + 3) / 4, 256, 0, stream>>>(off, deg, csr, dinv, h1, n_s, n_t);
  // layer 2: d_out = [relu(h1_s); u_t] @ W1  (final output)
  k_gemm2<<<(M + 127) / 128, 256, 0, stream>>>(h1, W1t, M, n_s, (float*)d_out);
}